// Round 9
// baseline (410.510 us; speedup 1.0000x reference)
//
#include <hip/hip_runtime.h>
#include <stdint.h>

// Problem constants (from reference)
#define B_    8
#define N_    20000
#define K_    12
#define F_    64
#define OUT_  128
#define D_    768            // K_*F_ flattened (s,f)
#define TM    32             // nodes per block (20000 = 625*32)
#define NTILES 625
#define LDE   776            // padded E row (bf16): 1552 B -> rows step 4 banks (2-way max, free)

typedef __attribute__((ext_vector_type(4))) float f32x4;
typedef __attribute__((ext_vector_type(8))) short short8;

// round-half-up fp32 -> bf16 (bits+0x8000, take high 16). Differs from RNE only
// on exact ties (measure-zero for continuous data); ~3x cheaper than manual RNE.
__device__ __forceinline__ uint32_t rhu(float x) {
    union { float f; uint32_t u; } c; c.f = x;
    return c.u + 0x8000u;
}
// pack two floats -> one dword of 2 bf16 (a in low ushort, b in high).
// Shift/and/or form -> compiler fuses to v_perm_b32.
__device__ __forceinline__ uint32_t pack2(float a, float b) {
    return (rhu(a) >> 16) | (rhu(b) & 0xFFFF0000u);
}

// Build a bf16x8 MFMA fragment from 8 consecutive fp32 values (16B-aligned).
__device__ __forceinline__ short8 ld_w8(const float* p) {
    f32x4 w0 = *(const f32x4*)p;
    f32x4 w1 = *(const f32x4*)(p + 4);
    union { short8 s8; uint32_t d[4]; } t;
    t.d[0] = pack2(w0[0], w0[1]);
    t.d[1] = pack2(w0[2], w0[3]);
    t.d[2] = pack2(w1[0], w1[1]);
    t.d[3] = pack2(w1[2], w1[3]);
    return t.s8;
}

__global__ __launch_bounds__(256) void paiconv_mfma_kernel(
    const float* __restrict__ x,      // [B,N,F]
    const int*   __restrict__ adj,    // [B,N,K]
    const float* __restrict__ adjw,   // [N,K,K]
    const float* __restrict__ W,      // [OUT,D] fp32
    const float* __restrict__ bias,   // [OUT]
    float*       __restrict__ out)    // [B,N,OUT]
{
    __shared__ __align__(16) union SM {
        ushort e[TM * LDE];            // 49664 B: ELU'd features, bf16 (phases 1-2)
        float  c[TM][OUT_ + 1];        // 16516 B: fp32 C tile (post-MFMA, padded +1)
    } sm;

    // XCD-batch affinity: with round-robin block->XCD dispatch, XCD i serves
    // batch i only -> x[b] (5.12 MB) ~fits that XCD's 4 MB L2. 5000 % 8 == 0.
    const int b    = blockIdx.x & 7;
    const int tile = blockIdx.x >> 3;
    const int tid  = threadIdx.x;

    // ---------- Phase 1 (VERIFIED R2/R6): gather -> mix -> ELU -> bf16 LDS ----------
    {
        const int nl = tid >> 3;            // node within tile (0..31)
        const int fb = (tid & 7) * 8;       // feature base (8 floats per thread)
        const int n  = tile * TM + nl;

        const int* ap = adj + ((size_t)b * N_ + n) * K_;
        float sp[K_][8];
        #pragma unroll
        for (int k = 0; k < K_; ++k) {
            const int id = ap[k];
            const float* xp = x + ((size_t)b * N_ + id) * F_ + fb;
            f32x4 v0 = *(const f32x4*)xp;
            f32x4 v1 = *(const f32x4*)(xp + 4);
            #pragma unroll
            for (int j = 0; j < 4; ++j) { sp[k][j] = v0[j]; sp[k][4 + j] = v1[j]; }
        }

        const float* wp = adjw + (size_t)n * (K_ * K_);
        #pragma unroll
        for (int s = 0; s < K_; ++s) {
            float acc1[8] = {0.f,0.f,0.f,0.f,0.f,0.f,0.f,0.f};
            #pragma unroll
            for (int k = 0; k < K_; ++k) {
                const float a = wp[k * K_ + s];
                #pragma unroll
                for (int j = 0; j < 8; ++j) acc1[j] = fmaf(sp[k][j], a, acc1[j]);
            }
            float ev[8];
            #pragma unroll
            for (int j = 0; j < 8; ++j) {
                float v = acc1[j];
                ev[j] = v > 0.f ? v : (__expf(v) - 1.f);   // ELU
            }
            uint4 pk;
            pk.x = pack2(ev[0], ev[1]);
            pk.y = pack2(ev[2], ev[3]);
            pk.z = pack2(ev[4], ev[5]);
            pk.w = pack2(ev[6], ev[7]);
            *(uint4*)&sm.e[nl * LDE + s * F_ + fb] = pk;   // 16B-aligned (1552 = 97*16)
        }
    }
    __syncthreads();

    // ---------- Phase 2: [32 x 768] x [768 x 128]^T via mfma_f32_16x16x32_bf16 ----------
    // W loaded fp32 straight from global (L2-resident), packed to bf16 in-register.
    const int wave = tid >> 6;          // 0..3 -> 32 output cols each
    const int lane = tid & 63;
    const int r    = lane & 15;
    const int kg   = lane >> 4;         // k-octet group 0..3

    f32x4 acc[2][2];
    #pragma unroll
    for (int i = 0; i < 2; ++i)
        #pragma unroll
        for (int j = 0; j < 2; ++j)
            acc[i][j] = (f32x4){0.f, 0.f, 0.f, 0.f};

    const int colbase = wave * 32;
    const ushort* e0  = &sm.e[r * LDE + kg * 8];
    const ushort* e1  = &sm.e[(16 + r) * LDE + kg * 8];
    const float*  wf0 = W + (size_t)(colbase + r) * D_ + kg * 8;
    const float*  wf1 = W + (size_t)(colbase + 16 + r) * D_ + kg * 8;

    for (int kb = 0; kb < D_; kb += 32) {
        short8 a0 = *(const short8*)(e0 + kb);
        short8 a1 = *(const short8*)(e1 + kb);
        short8 b0 = ld_w8(wf0 + kb);
        short8 b1 = ld_w8(wf1 + kb);
        acc[0][0] = __builtin_amdgcn_mfma_f32_16x16x32_bf16(a0, b0, acc[0][0], 0, 0, 0);
        acc[0][1] = __builtin_amdgcn_mfma_f32_16x16x32_bf16(a0, b1, acc[0][1], 0, 0, 0);
        acc[1][0] = __builtin_amdgcn_mfma_f32_16x16x32_bf16(a1, b0, acc[1][0], 0, 0, 0);
        acc[1][1] = __builtin_amdgcn_mfma_f32_16x16x32_bf16(a1, b1, acc[1][1], 0, 0, 0);
    }

    // ---------- C -> LDS via C/D layout (col=lane&15, row=4*(lane>>4)+j) ----------
    __syncthreads();   // all E reads done before overwriting the union
    #pragma unroll
    for (int mt = 0; mt < 2; ++mt)
        #pragma unroll
        for (int nt = 0; nt < 2; ++nt)
            #pragma unroll
            for (int j = 0; j < 4; ++j)
                sm.c[mt * 16 + kg * 4 + j][colbase + nt * 16 + r] = acc[mt][nt][j];
    __syncthreads();

    // ---------- Epilogue (VERIFIED R2/R6): bias + ELU + mask + coalesced store ----------
    {
        const int nl = tid >> 3;
        const int ob = (tid & 7) * 16;
        const int n  = tile * TM + nl;
        float* op = out + ((size_t)b * N_ + n) * OUT_ + ob;
        float vv[16];
        #pragma unroll
        for (int jj = 0; jj < 16; ++jj) {
            float v = sm.c[nl][ob + jj] + bias[ob + jj];
            v = v > 0.f ? v : (__expf(v) - 1.f);   // ELU
            if (n == N_ - 1) v = 0.f;              // zero-pad mask (last node, all batches)
            vv[jj] = v;
        }
        #pragma unroll
        for (int q = 0; q < 4; ++q) {
            f32x4 o4 = { vv[q*4+0], vv[q*4+1], vv[q*4+2], vv[q*4+3] };
            *(f32x4*)(op + q * 4) = o4;
        }
    }
}

extern "C" void kernel_launch(void* const* d_in, const int* in_sizes, int n_in,
                              void* d_out, int out_size, void* d_ws, size_t ws_size,
                              hipStream_t stream) {
    const float* x    = (const float*)d_in[0];
    const int*   adj  = (const int*)d_in[1];
    // d_in[2] = kernal_weight: unused by the forward pass
    const float* adjw = (const float*)d_in[3];
    const float* W    = (const float*)d_in[4];
    const float* bias = (const float*)d_in[5];
    float* out = (float*)d_out;

    paiconv_mfma_kernel<<<B_ * NTILES, 256, 0, stream>>>(x, adj, adjw, W, bias, out);
}